// Round 11
// baseline (973.890 us; speedup 1.0000x reference)
//
#include <hip/hip_runtime.h>
#include <hip/hip_bf16.h>

// GPT forward: B=2, T=1024, D=1024, H=16, HD=64, L=4, V=32000
// R11: attention rewritten as kv-split flash: grid (32 q-subtiles x 32 bh),
//      4 waves/block each handling strided kv-tiles of the SAME 32 q-rows,
//      (m,l,O) combine via LDS. 3 blocks/CU, 12 waves/CU, uniform load.
//      k_bcat folded into k_tconv_all.

typedef __attribute__((ext_vector_type(8))) short s16x8;
typedef __attribute__((ext_vector_type(4))) float fx4;

__device__ __forceinline__ unsigned short f2bf(float f) {
    union { float f; unsigned int u; } v; v.f = f;
    unsigned int r = v.u + 0x7FFFu + ((v.u >> 16) & 1u);
    return (unsigned short)(r >> 16);
}

__device__ __forceinline__ void gload16(const short* g, short* l) {
    __builtin_amdgcn_global_load_lds((const __attribute__((address_space(1))) void*)g,
                                     (__attribute__((address_space(3))) void*)l, 16, 0, 0);
}

__device__ __forceinline__ unsigned cvtpk(float a, float b) {
    unsigned r;
    asm("v_cvt_pk_bf16_f32 %0, %1, %2" : "=v"(r) : "v"(a), "v"(b));
    return r;
}

// ---------------- embed + LN fused (row-local) ----------------
__global__ __launch_bounds__(256) void k_embedln(const int* __restrict__ idx,
                                                 const float* __restrict__ tok,
                                                 const float* __restrict__ pos,
                                                 const float* __restrict__ lw,
                                                 const float* __restrict__ lb,
                                                 float* __restrict__ x,
                                                 short* __restrict__ out) {
    int r = blockIdx.x;
    int t = r & 1023;
    int tokid = idx[r];
    int tid = threadIdx.x;
    float4 v = ((const float4*)(tok + (size_t)tokid * 1024))[tid];
    float4 vp = ((const float4*)(pos + (size_t)t * 1024))[tid];
    v.x += vp.x; v.y += vp.y; v.z += vp.z; v.w += vp.w;
    ((float4*)(x + (size_t)r * 1024))[tid] = v;
    float s = v.x + v.y + v.z + v.w;
    float ss = v.x*v.x + v.y*v.y + v.z*v.z + v.w*v.w;
    __shared__ float red[8];
    #pragma unroll
    for (int off = 32; off; off >>= 1) { s += __shfl_down(s, off); ss += __shfl_down(ss, off); }
    int wid = tid >> 6;
    if ((tid & 63) == 0) { red[wid] = s; red[4 + wid] = ss; }
    __syncthreads();
    s = red[0] + red[1] + red[2] + red[3];
    ss = red[4] + red[5] + red[6] + red[7];
    float mean = s * (1.0f / 1024.0f);
    float var = ss * (1.0f / 1024.0f) - mean * mean;
    float rstd = rsqrtf(var + 1e-5f);
    float4 wv = ((const float4*)lw)[tid];
    float4 bv = ((const float4*)lb)[tid];
    union { unsigned short us[4]; unsigned long long ll; } pk;
    pk.us[0] = f2bf((v.x - mean) * rstd * wv.x + bv.x);
    pk.us[1] = f2bf((v.y - mean) * rstd * wv.y + bv.y);
    pk.us[2] = f2bf((v.z - mean) * rstd * wv.z + bv.z);
    pk.us[3] = f2bf((v.w - mean) * rstd * wv.w + bv.w);
    ((unsigned long long*)(out + (size_t)r * 1024))[tid] = pk.ll;
}

// ---------------- layernorm (row of 1024), bf16 out ----------------
__global__ __launch_bounds__(256) void k_ln(const float* __restrict__ x,
                                            const float* __restrict__ w,
                                            const float* __restrict__ b,
                                            short* __restrict__ out) {
    int r = blockIdx.x;
    int tid = threadIdx.x;
    float4 v = ((const float4*)(x + (size_t)r * 1024))[tid];
    float s = v.x + v.y + v.z + v.w;
    float ss = v.x*v.x + v.y*v.y + v.z*v.z + v.w*v.w;
    __shared__ float red[8];
    #pragma unroll
    for (int off = 32; off; off >>= 1) { s += __shfl_down(s, off); ss += __shfl_down(ss, off); }
    int wid = tid >> 6;
    if ((tid & 63) == 0) { red[wid] = s; red[4 + wid] = ss; }
    __syncthreads();
    s = red[0] + red[1] + red[2] + red[3];
    ss = red[4] + red[5] + red[6] + red[7];
    float mean = s * (1.0f / 1024.0f);
    float var = ss * (1.0f / 1024.0f) - mean * mean;
    float rstd = rsqrtf(var + 1e-5f);
    float4 wv = ((const float4*)w)[tid];
    float4 bv = ((const float4*)b)[tid];
    union { unsigned short us[4]; unsigned long long ll; } pk;
    pk.us[0] = f2bf((v.x - mean) * rstd * wv.x + bv.x);
    pk.us[1] = f2bf((v.y - mean) * rstd * wv.y + bv.y);
    pk.us[2] = f2bf((v.z - mean) * rstd * wv.z + bv.z);
    pk.us[3] = f2bf((v.w - mean) * rstd * wv.w + bv.w);
    ((unsigned long long*)(out + (size_t)r * 1024))[tid] = pk.ll;
}

// ---------------- splitK reduce + bias + residual + LN fused ----------------
__global__ __launch_bounds__(256) void k_redln(const float* __restrict__ part,
                                               const float* __restrict__ bias,
                                               float* __restrict__ x,
                                               const float* __restrict__ lw,
                                               const float* __restrict__ lb,
                                               short* __restrict__ out) {
    const size_t PS = (size_t)2048 * 1024;
    const int r = blockIdx.x;
    const int tid = threadIdx.x;
    const size_t base = (size_t)r * 1024 + tid * 4;
    float4 a = *(const float4*)(part + base);
    float4 b = *(const float4*)(part + PS + base);
    float4 c = *(const float4*)(part + 2 * PS + base);
    float4 d = *(const float4*)(part + 3 * PS + base);
    float4 v = *(const float4*)(x + base);
    float4 bb = *(const float4*)(bias + tid * 4);
    v.x += a.x + b.x + c.x + d.x + bb.x;
    v.y += a.y + b.y + c.y + d.y + bb.y;
    v.z += a.z + b.z + c.z + d.z + bb.z;
    v.w += a.w + b.w + c.w + d.w + bb.w;
    *(float4*)(x + base) = v;
    float s = v.x + v.y + v.z + v.w;
    float ss = v.x*v.x + v.y*v.y + v.z*v.z + v.w*v.w;
    __shared__ float red[8];
    #pragma unroll
    for (int off = 32; off; off >>= 1) { s += __shfl_down(s, off); ss += __shfl_down(ss, off); }
    int wid = tid >> 6;
    if ((tid & 63) == 0) { red[wid] = s; red[4 + wid] = ss; }
    __syncthreads();
    s = red[0] + red[1] + red[2] + red[3];
    ss = red[4] + red[5] + red[6] + red[7];
    float mean = s * (1.0f / 1024.0f);
    float var = ss * (1.0f / 1024.0f) - mean * mean;
    float rstd = rsqrtf(var + 1e-5f);
    float4 wv = ((const float4*)lw)[tid];
    float4 bv = ((const float4*)lb)[tid];
    union { unsigned short us[4]; unsigned long long ll; } pk;
    pk.us[0] = f2bf((v.x - mean) * rstd * wv.x + bv.x);
    pk.us[1] = f2bf((v.y - mean) * rstd * wv.y + bv.y);
    pk.us[2] = f2bf((v.z - mean) * rstd * wv.z + bv.z);
    pk.us[3] = f2bf((v.w - mean) * rstd * wv.w + bv.w);
    ((unsigned long long*)(out + (size_t)r * 1024))[tid] = pk.ll;
}

// ---------------- batched transpose+convert (+ qkv-bias concat), one dispatch ----------------
__global__ __launch_bounds__(256) void k_tconv_all(
        const float* __restrict__ Wq, const float* __restrict__ Wk,
        const float* __restrict__ Wv, const float* __restrict__ Wo,
        const float* __restrict__ W1, const float* __restrict__ W2,
        const float* __restrict__ Wh,
        const float* __restrict__ bq, const float* __restrict__ bk,
        const float* __restrict__ bv,
        short* __restrict__ wqkv, short* __restrict__ wo,
        short* __restrict__ w1, short* __restrict__ w2, short* __restrict__ wh,
        float* __restrict__ bqkv) {
    const int bid = blockIdx.x;
    if (bid >= 20288) {
        int i = (bid - 20288) * 256 + threadIdx.x;      // 4*3072
        int lq = i / 3072, c = i % 3072;
        float v = (c < 1024) ? bq[lq*1024 + c] : ((c < 2048) ? bk[lq*1024 + c - 1024] : bv[lq*1024 + c - 2048]);
        bqkv[i] = v;
        return;
    }
    const float* src; short* dst; int K, N, tile;
    if (bid < 4096) {
        int seg = bid >> 10;
        int r = bid & 1023;
        int l = r >> 8; tile = r & 255;
        K = 1024; N = 1024;
        if (seg == 0)      { src = Wq + (size_t)l * 1048576; dst = wqkv + (size_t)l * 3145728; }
        else if (seg == 1) { src = Wk + (size_t)l * 1048576; dst = wqkv + (size_t)l * 3145728 + 1048576; }
        else if (seg == 2) { src = Wv + (size_t)l * 1048576; dst = wqkv + (size_t)l * 3145728 + 2097152; }
        else               { src = Wo + (size_t)l * 1048576; dst = wo + (size_t)l * 1048576; }
    } else if (bid < 8192) {
        int r = bid - 4096; int l = r >> 10; tile = r & 1023;
        K = 1024; N = 4096; src = W1 + (size_t)l * 4194304; dst = w1 + (size_t)l * 4194304;
    } else if (bid < 12288) {
        int r = bid - 8192; int l = r >> 10; tile = r & 1023;
        K = 4096; N = 1024; src = W2 + (size_t)l * 4194304; dst = w2 + (size_t)l * 4194304;
    } else {
        tile = bid - 12288; K = 1024; N = 32000; src = Wh; dst = wh;
    }
    const int nTiles = N >> 6;
    const int kt = tile / nTiles, ntl = tile - kt * nTiles;
    const int n0 = ntl * 64, k0 = kt * 64;

    __shared__ float tl[64][65];
    const int tid = threadIdx.x;
    const int c4 = tid & 15, rr = tid >> 4;
    #pragma unroll
    for (int j = 0; j < 4; j++) {
        int row = rr + j * 16;
        float4 vv = *(const float4*)(src + (size_t)(k0 + row) * N + n0 + c4 * 4);
        tl[row][c4*4+0] = vv.x; tl[row][c4*4+1] = vv.y;
        tl[row][c4*4+2] = vv.z; tl[row][c4*4+3] = vv.w;
    }
    __syncthreads();
    const int c8 = tid & 7, r2 = tid >> 3;
    #pragma unroll
    for (int j = 0; j < 2; j++) {
        int nrow = r2 + j * 32;
        union { unsigned short us[8]; s16x8 v; } pk;
        #pragma unroll
        for (int e = 0; e < 8; e++) pk.us[e] = f2bf(tl[c8*8+e][nrow]);
        *(s16x8*)&dst[(size_t)(n0 + nrow) * K + k0 + c8 * 8] = pk.v;
    }
}

// ---------------- 128-class GEMM (m97 structure), EPI + split-K support ----------------
// EPI: 0 = bias->bf16; 1 = f32 + residual; 2 = bias+GELU->bf16; 3 = f32 partial
// (no bias); 4 = QKV: bias->bf16 for Q/K cols, V cols transposed bf16 -> vtout
template<int MF, int EPI>
__global__ __launch_bounds__(256) void k_gemm(const short* __restrict__ A, const short* __restrict__ Bt,
                                              const float* bias, const float* res, void* Cout,
                                              short* vtout,
                                              int M, int N, int Kstride, int kLen,
                                              int mTiles, int nParts) {
    constexpr int BM = MF * 32;
    constexpr int IA = BM / 32;
    __shared__ __align__(16) short lA[BM * 64];
    __shared__ __align__(16) short lB[128 * 64];
    const int tid = threadIdx.x;
    const int l = tid & 63, w = tid >> 6;
    const int wr = w >> 1, wc = w & 1;
    const int per = gridDim.x >> 3;
    const int s2 = (blockIdx.x & 7) * per + (blockIdx.x >> 3);
    const int totPerN = mTiles * nParts;
    const int nt = s2 / totPerN;
    const int rem = s2 - nt * totPerN;
    const int part = rem / mTiles, mt = rem - part * mTiles;
    const int k0 = part * kLen;
    const int m0 = mt * BM, n0 = nt * 128;
    const int cl = l & 15, rh = l >> 4;
    fx4 acc[MF][4] = {};

    const int lr = l >> 3, c8 = l & 7;
    const short* pa[IA];
    const short* pb[4];
    #pragma unroll
    for (int j = 0; j < IA; j++) {
        const int row = w * (BM / 4) + j * 8 + lr;
        pa[j] = A + (size_t)(m0 + row) * Kstride + k0 + ((c8 ^ (row & 7)) << 3);
    }
    #pragma unroll
    for (int j = 0; j < 4; j++) {
        const int row = w * 32 + j * 8 + lr;
        pb[j] = Bt + (size_t)(n0 + row) * Kstride + k0 + ((c8 ^ (row & 7)) << 3);
    }

    for (int kt = 0; kt < kLen; kt += 64) {
        #pragma unroll
        for (int j = 0; j < IA; j++)
            gload16(pa[j] + kt, &lA[(w * (BM / 4) + j * 8) * 64]);
        #pragma unroll
        for (int j = 0; j < 4; j++)
            gload16(pb[j] + kt, &lB[(w * 32 + j * 8) * 64]);
        __syncthreads();
        #pragma unroll
        for (int kk = 0; kk < 2; kk++) {
            s16x8 af[MF], bfr[4];
            const int kc = kk * 4 + rh;
            const int ko = (kc ^ (cl & 7)) * 8;
            #pragma unroll
            for (int mf = 0; mf < MF; mf++)
                af[mf] = *(const s16x8*)&lA[(wr * (MF * 16) + mf * 16 + cl) * 64 + ko];
            #pragma unroll
            for (int nf = 0; nf < 4; nf++)
                bfr[nf] = *(const s16x8*)&lB[(wc * 64 + nf * 16 + cl) * 64 + ko];
            #pragma unroll
            for (int mf = 0; mf < MF; mf++)
                #pragma unroll
                for (int nf = 0; nf < 4; nf++)
                    acc[mf][nf] = __builtin_amdgcn_mfma_f32_16x16x32_bf16(af[mf], bfr[nf], acc[mf][nf], 0, 0, 0);
        }
        __syncthreads();
    }
    float* Cp = (float*)Cout + (size_t)part * M * N;
    #pragma unroll
    for (int nf = 0; nf < 4; nf++) {
        const int col = n0 + wc * 64 + nf * 16 + cl;
        const float bv = (EPI == 3) ? 0.0f : bias[col];
        #pragma unroll
        for (int mf = 0; mf < MF; mf++) {
            const int rbase = m0 + wr * (MF * 16) + mf * 16 + rh * 4;
            if constexpr (EPI == 4) {
                float vv[4];
                #pragma unroll
                for (int r = 0; r < 4; r++) vv[r] = acc[mf][nf][r] + bv;
                if (n0 >= 2048) {
                    const int cc = col - 2048;
                    const int bidx = rbase >> 10, t0v = rbase & 1023;
                    uint2 pk2;
                    pk2.x = cvtpk(vv[0], vv[1]);
                    pk2.y = cvtpk(vv[2], vv[3]);
                    *(uint2*)&vtout[(size_t)((bidx * 16 + (cc >> 6)) * 64 + (cc & 63)) * 1024 + t0v] = pk2;
                } else {
                    #pragma unroll
                    for (int r = 0; r < 4; r++)
                        ((unsigned short*)Cout)[(size_t)(rbase + r) * N + col] = f2bf(vv[r]);
                }
            } else {
                #pragma unroll
                for (int r = 0; r < 4; r++) {
                    float v = acc[mf][nf][r] + bv;
                    const size_t off = (size_t)(rbase + r) * N + col;
                    if constexpr (EPI == 0) {
                        ((unsigned short*)Cout)[off] = f2bf(v);
                    } else if constexpr (EPI == 1) {
                        ((float*)Cout)[off] = v + res[off];
                    } else if constexpr (EPI == 2) {
                        v = 0.5f * v * (1.0f + erff(v * 0.70710678118654752f));
                        ((unsigned short*)Cout)[off] = f2bf(v);
                    } else {
                        Cp[off] = v;
                    }
                }
            }
        }
    }
}

// ---------------- 8-phase 256x256 GEMM (head), f32 out, no bias ----------------
#define PH_CORE(MB) \
    __builtin_amdgcn_s_barrier(); \
    __builtin_amdgcn_s_setprio(1); \
    _Pragma("unroll") \
    for (int nf_ = 0; nf_ < 4; ++nf_) { \
        acc[MB][nf_]   = __builtin_amdgcn_mfma_f32_16x16x32_bf16(af[0][0], bf[nf_][0], acc[MB][nf_], 0, 0, 0); \
        acc[MB][nf_]   = __builtin_amdgcn_mfma_f32_16x16x32_bf16(af[0][1], bf[nf_][1], acc[MB][nf_], 0, 0, 0); \
        acc[MB+1][nf_] = __builtin_amdgcn_mfma_f32_16x16x32_bf16(af[1][0], bf[nf_][0], acc[MB+1][nf_], 0, 0, 0); \
        acc[MB+1][nf_] = __builtin_amdgcn_mfma_f32_16x16x32_bf16(af[1][1], bf[nf_][1], acc[MB+1][nf_], 0, 0, 0); \
    } \
    __builtin_amdgcn_s_setprio(0);

#define PHN(MB) \
    PH_CORE(MB) \
    asm volatile("" ::: "memory"); \
    __builtin_amdgcn_s_barrier(); \
    asm volatile("" ::: "memory");

#define PHW(MB) \
    PH_CORE(MB) \
    asm volatile("s_waitcnt vmcnt(4)" ::: "memory"); \
    __builtin_amdgcn_s_barrier(); \
    asm volatile("" ::: "memory");

__global__ __launch_bounds__(512, 1)
void k_gemm8(const short* __restrict__ A, const short* __restrict__ Bt,
             float* __restrict__ C, int M, int N, int K, int mTiles) {
    __shared__ __align__(16) short lA[2][256 * 64];
    __shared__ __align__(16) short lB[2][256 * 64];
    const int tid = threadIdx.x;
    const int l = tid & 63, w = tid >> 6;
    const int wr = w >> 2, wc = w & 3;
    const int per = gridDim.x >> 3;
    const int s2 = (blockIdx.x & 7) * per + (blockIdx.x >> 3);
    const int nt0 = s2 / mTiles, mt = s2 - nt0 * mTiles;
    const int m0 = mt * 256, n0 = nt0 * 256;
    const int cl = l & 15, rh = l >> 4;

    fx4 acc[8][4] = {};

    const int srow = tid >> 3, sc8 = tid & 7;
    const short* pA[2][2]; const short* pB[2][2];
    #pragma unroll
    for (int hh = 0; hh < 2; ++hh)
        #pragma unroll
        for (int j = 0; j < 2; ++j) {
            const int row = hh * 128 + j * 64 + srow;
            const int cg = (sc8 ^ (row & 7)) << 3;
            pA[hh][j] = A + (size_t)(m0 + row) * K + cg;
            pB[hh][j] = Bt + (size_t)(n0 + row) * K + cg;
        }

    auto stageA = [&](int b, int hh, int kt) {
        #pragma unroll
        for (int j = 0; j < 2; ++j)
            gload16(pA[hh][j] + (kt << 6), &lA[b][(hh * 128 + j * 64 + w * 8) * 64]);
    };
    auto stageB = [&](int b, int hh, int kt) {
        #pragma unroll
        for (int j = 0; j < 2; ++j)
            gload16(pB[hh][j] + (kt << 6), &lB[b][(hh * 128 + j * 64 + w * 8) * 64]);
    };
    auto readA = [&](int b, int mf, int kk) -> s16x8 {
        const int row = wr * 128 + mf * 16 + cl;
        return *(const s16x8*)&lA[b][(row << 6) + (((kk * 4 + rh) ^ (row & 7)) << 3)];
    };
    auto readB = [&](int b, int nf, int kk) -> s16x8 {
        const int row = wc * 64 + nf * 16 + cl;
        return *(const s16x8*)&lB[b][(row << 6) + (((kk * 4 + rh) ^ (row & 7)) << 3)];
    };

    const int NT = K >> 6;
    stageA(0, 0, 0); stageA(0, 1, 0);
    stageB(0, 0, 0); stageB(0, 1, 0);
    stageB(1, 0, 1); stageB(1, 1, 1);
    asm volatile("s_waitcnt vmcnt(4)" ::: "memory");
    __builtin_amdgcn_s_barrier();
    asm volatile("" ::: "memory");

    s16x8 bf[4][2], af[2][2];
    for (int c = 0; c < (NT >> 1); ++c) {
        const int kt = c << 1;
        const int k1 = kt + 1;
        const int k2 = (kt + 2 < NT) ? kt + 2 : NT - 1;
        const int k3 = (kt + 3 < NT) ? kt + 3 : NT - 1;

        #pragma unroll
        for (int nf = 0; nf < 4; ++nf) { bf[nf][0] = readB(0, nf, 0); bf[nf][1] = readB(0, nf, 1); }
        af[0][0] = readA(0, 0, 0); af[0][1] = readA(0, 0, 1);
        af[1][0] = readA(0, 1, 0); af[1][1] = readA(0, 1, 1);
        stageA(1, 0, k1); stageA(1, 1, k1);
        PHN(0)
        af[0][0] = readA(0, 2, 0); af[0][1] = readA(0, 2, 1);
        af[1][0] = readA(0, 3, 0); af[1][1] = readA(0, 3, 1);
        stageB(0, 0, k2);
        PHN(2)
        af[0][0] = readA(0, 4, 0); af[0][1] = readA(0, 4, 1);
        af[1][0] = readA(0, 5, 0); af[1][1] = readA(0, 5, 1);
        stageB(0, 1, k2);
        PHN(4)
        af[0][0] = readA(0, 6, 0); af[0][1] = readA(0, 6, 1);
        af[1][0] = readA(0, 7, 0); af[1][1] = readA(0, 7, 1);
        PHW(6)
        #pragma unroll
        for (int nf = 0; nf < 4; ++nf) { bf[nf][0] = readB(1, nf, 0); bf[nf][1] = readB(1, nf, 1); }
        af[0][0] = readA(1, 0, 0); af[0][1] = readA(1, 0, 1);
        af[1][0] = readA(1, 1, 0); af[1][1] = readA(1, 1, 1);
        stageA(0, 0, k2);
        PHN(0)
        af[0][0] = readA(1, 2, 0); af[0][1] = readA(1, 2, 1);
        af[1][0] = readA(1, 3, 0); af[1][1] = readA(1, 3, 1);
        stageA(0, 1, k2);
        PHN(2)
        af[0][0] = readA(1, 4, 0); af[0][1] = readA(1, 4, 1);
        af[1][0] = readA(1, 5, 0); af[1][1] = readA(1, 5, 1);
        stageB(1, 0, k3);
        PHN(4)
        af[0][0] = readA(1, 6, 0); af[0][1] = readA(1, 6, 1);
        af[1][0] = readA(1, 7, 0); af[1][1] = readA(1, 7, 1);
        stageB(1, 1, k3);
        PHW(6)
    }

    float* eld = (float*)((char*)&lA[0][0] + w * 4352);
    const int erow = l >> 4, ec4 = (l & 15) * 4;
    #pragma unroll
    for (int mf = 0; mf < 8; ++mf) {
        #pragma unroll
        for (int nf = 0; nf < 4; ++nf)
            #pragma unroll
            for (int r = 0; r < 4; ++r)
                eld[(rh * 4 + r) * 68 + nf * 16 + cl] = acc[mf][nf][r];
        asm volatile("s_waitcnt lgkmcnt(0)" ::: "memory");
        #pragma unroll
        for (int s = 0; s < 4; ++s) {
            const int rr2 = s * 4 + erow;
            float4 vv = *(const float4*)&eld[rr2 * 68 + ec4];
            *(float4*)&C[(size_t)(m0 + wr * 128 + mf * 16 + rr2) * N + n0 + wc * 64 + ec4] = vv;
        }
        asm volatile("s_waitcnt lgkmcnt(0)" ::: "memory");
    }
}

// ---------------- fused causal attention: kv-split flash ----------------
// grid (32 s, 32 bh). Block: 32 q-rows (s*32..+31), 4 waves each handle
// kv-tiles t = w, w+4, ... (64-wide). Per-wave online softmax (same inner
// body as R6/R9), then (m,l,O) 4-way combine via LDS. ~3 blocks/CU.
__global__ __launch_bounds__(256) void k_attn(const short* __restrict__ qkv,
                                              const short* __restrict__ vt,
                                              short* __restrict__ y) {
    const int bh = blockIdx.y, s = blockIdx.x;
    const int b = bh >> 4, h = bh & 15;
    const int w = threadIdx.x >> 6, l = threadIdx.x & 63;
    const int cl = l & 15, rh = l >> 4;
    const int q0 = s * 32;
    const short* qbase = qkv + (size_t)b * 1024 * 3072 + h * 64;
    const short* kbase = qbase + 1024;
    const short* vbase = vt + (size_t)bh * 64 * 1024;
    __shared__ __align__(16) short plds[4][32][64];
    __shared__ __align__(16) float Olds[4][32][68];
    __shared__ float mld[4][32], lld[4][32];
    char* pbase = (char*)&plds[w][0][0];

    s16x8 qf[2][2];
    #pragma unroll
    for (int n = 0; n < 2; n++)
        #pragma unroll
        for (int kf = 0; kf < 2; kf++)
            qf[n][kf] = *(const s16x8*)&qbase[(size_t)(q0 + n * 16 + cl) * 3072 + kf * 32 + rh * 8];

    fx4 oacc[4][2] = {};
    float mrow[2] = {-3e38f, -3e38f}, lrow[2] = {0.0f, 0.0f};
    const float SC = 0.125f * 1.44269504088896f;

    const int ntile = (((s * 32) + 31) >> 6) + 1;
    for (int it = w; it < ntile; it += 4) {
        const int t0 = it * 64;
        fx4 sa[4][2] = {};
        #pragma unroll
        for (int kf = 0; kf < 2; kf++) {
            s16x8 kfr[4];
            #pragma unroll
            for (int m = 0; m < 4; m++)
                kfr[m] = *(const s16x8*)&kbase[(size_t)(t0 + m * 16 + cl) * 3072 + kf * 32 + rh * 8];
            #pragma unroll
            for (int m = 0; m < 4; m++)
                #pragma unroll
                for (int n = 0; n < 2; n++)
                    sa[m][n] = __builtin_amdgcn_mfma_f32_16x16x32_bf16(kfr[m], qf[n][kf], sa[m][n], 0, 0, 0);
        }
        const bool domask = (t0 + 63) > q0;
        #pragma unroll
        for (int n = 0; n < 2; n++) {
            const int qq = q0 + n * 16 + cl;
            float tmax = -3e38f;
            #pragma unroll
            for (int m = 0; m < 4; m++)
                #pragma unroll
                for (int r = 0; r < 4; r++) {
                    float v = sa[m][n][r] * SC;
                    if (domask && (t0 + m * 16 + rh * 4 + r) > qq) v = -3e38f;
                    sa[m][n][r] = v;
                    tmax = fmaxf(tmax, v);
                }
            tmax = fmaxf(tmax, __shfl_xor(tmax, 16));
            tmax = fmaxf(tmax, __shfl_xor(tmax, 32));
            const float mnew = fmaxf(mrow[n], tmax);
            const float alpha = exp2f(mrow[n] - mnew);
            mrow[n] = mnew;
            float rsum = 0.0f;
            #pragma unroll
            for (int m = 0; m < 4; m++)
                #pragma unroll
                for (int r = 0; r < 4; r++) {
                    float p = exp2f(sa[m][n][r] - mnew);
                    sa[m][n][r] = p;
                    rsum += p;
                }
            rsum += __shfl_xor(rsum, 16);
            rsum += __shfl_xor(rsum, 32);
            lrow[n] = lrow[n] * alpha + rsum;
            #pragma unroll
            for (int mp = 0; mp < 4; mp++)
                #pragma unroll
                for (int r = 0; r < 4; r++)
                    oacc[mp][n][r] *= alpha;
        }
        #pragma unroll
        for (int n = 0; n < 2; n++) {
            const int qr = n * 16 + cl;
            const int sw = (qr & 7) << 4;
            #pragma unroll
            for (int m = 0; m < 4; m++) {
                uint2 pk2;
                pk2.x = cvtpk(sa[m][n][0], sa[m][n][1]);
                pk2.y = cvtpk(sa[m][n][2], sa[m][n][3]);
                const int off = qr * 128 + ((m * 32 + rh * 8) ^ sw);
                *(uint2*)(pbase + off) = pk2;
            }
        }
        s16x8 pb2[2][2];
        #pragma unroll
        for (int n = 0; n < 2; n++) {
            const int qr = n * 16 + cl;
            const int sw = (qr & 7) << 4;
            #pragma unroll
            for (int kf = 0; kf < 2; kf++)
                pb2[n][kf] = *(const s16x8*)(pbase + qr * 128 + ((kf * 64 + rh * 16) ^ sw));
        }
        s16x8 vf[4][2];
        #pragma unroll
        for (int mp = 0; mp < 4; mp++)
            #pragma unroll
            for (int kf = 0; kf < 2; kf++)
                vf[mp][kf] = *(const s16x8*)&vbase[(size_t)(mp * 16 + cl) * 1024 + t0 + kf * 32 + rh * 8];
        #pragma unroll
        for (int mp = 0; mp < 4; mp++)
            #pragma unroll
            for (int n = 0; n < 2; n++)
                #pragma unroll
                for (int kf = 0; kf < 2; kf++)
                    oacc[mp][n] = __builtin_amdgcn_mfma_f32_16x16x32_bf16(vf[mp][kf], pb2[n][kf], oacc[mp][n], 0, 0, 0);
    }
    // write partials
    if (rh == 0) {
        mld[w][cl] = mrow[0]; mld[w][16 + cl] = mrow[1];
        lld[w][cl] = lrow[0]; lld[w][16 + cl] = lrow[1];
    }
    #pragma unroll
    for (int mp = 0; mp < 4; ++mp)
        #pragma unroll
        for (int n = 0; n < 2; ++n)
            *(fx4*)&Olds[w][n * 16 + cl][mp * 16 + rh * 4] = oacc[mp][n];
    __syncthreads();
    // combine: wave w owns q-rows w*8..w*8+7; lane covers 8 hd values
    {
        const int qr = w * 8 + (l >> 3);
        const int hd0 = (l & 7) * 8;
        float m0 = mld[0][qr], m1 = mld[1][qr], m2 = mld[2][qr], m3 = mld[3][qr];
        float M = fmaxf(fmaxf(m0, m1), fmaxf(m2, m3));
        float sc0 = exp2f(m0 - M), sc1 = exp2f(m1 - M);
        float sc2 = exp2f(m2 - M), sc3 = exp2f(m3 - M);
        float L = lld[0][qr] * sc0 + lld[1][qr] * sc1 + lld[2][qr] * sc2 + lld[3][qr] * sc3;
        const float rinv = 1.0f / L;
        float o[8];
        #pragma unroll
        for (int e = 0; e < 8; ++e) o[e] = 0.0f;
        const float scw[4] = {sc0, sc1, sc2, sc3};
        #pragma unroll
        for (int ww = 0; ww < 4; ++ww) {
            float4 a = *(const float4*)&Olds[ww][qr][hd0];
            float4 bb = *(const float4*)&Olds[ww][qr][hd0 + 4];
            o[0] += scw[ww] * a.x;  o[1] += scw[ww] * a.y;
            o[2] += scw[ww] * a.z;  o[3] += scw[ww] * a.w;
            o[4] += scw[ww] * bb.x; o[5] += scw[ww] * bb.y;
            o[6] += scw[ww] * bb.z; o[7] += scw[ww] * bb.w;
        }
        union { unsigned u[4]; s16x8 v; } pk;
        pk.u[0] = cvtpk(o[0] * rinv, o[1] * rinv);
        pk.u[1] = cvtpk(o[2] * rinv, o[3] * rinv);
        pk.u[2] = cvtpk(o[4] * rinv, o[5] * rinv);
        pk.u[3] = cvtpk(o[6] * rinv, o[7] * rinv);
        *(s16x8*)&y[(size_t)(b * 1024 + q0 + qr) * 1024 + h * 64 + hd0] = pk.v;
    }
}

// ---------------- host launcher ----------------
extern "C" void kernel_launch(void* const* d_in, const int* in_sizes, int n_in,
                              void* d_out, int out_size, void* d_ws, size_t ws_size,
                              hipStream_t stream) {
    const int*   idx   = (const int*)d_in[0];
    const float* tok   = (const float*)d_in[1];
    const float* pos   = (const float*)d_in[2];
    const float* ln1w  = (const float*)d_in[3];
    const float* ln1b  = (const float*)d_in[4];
    const float* Wq    = (const float*)d_in[5];
    const float* bq    = (const float*)d_in[6];
    const float* Wk    = (const float*)d_in[7];
    const float* bk    = (const float*)d_in[8];
    const float* Wv    = (const float*)d_in[9];
    const float* bv    = (const float*)d_in[10];
    const float* Wo    = (const float*)d_in[11];
    const float* bo    = (const float*)d_in[12];
    const float* ln2w  = (const float*)d_in[13];
    const float* ln2b  = (const float*)d_in[14];
    const float* W1    = (const float*)d_in[15];
    const float* b1    = (const float*)d_in[16];
    const float* W2    = (const float*)d_in[17];
    const float* b2    = (const float*)d_in[18];
    const float* lnfw  = (const float*)d_in[19];
    const float* lnfb  = (const float*)d_in[20];
    const float* headw = (const float*)d_in[21];

    char* ws = (char*)d_ws;
    size_t off = 0;
    auto nalloc = [&](size_t bytes) -> char* {
        char* p = ws + off;
        off = (off + bytes + 255) & ~(size_t)255;
        return p;
    };
    float* x     = (float*)nalloc((size_t)2048 * 1024 * 4);
    short* h     = (short*)nalloc((size_t)2048 * 1024 * 2);
    short* qkv   = (short*)nalloc((size_t)2048 * 3072 * 2);
    short* vtb   = (short*)nalloc((size_t)32 * 64 * 1024 * 2);
    short* y     = (short*)nalloc((size_t)2048 * 1024 * 2);
    short* u     = (short*)nalloc((size_t)2048 * 4096 * 2);
    float* mpart = (float*)nalloc((size_t)4 * 2048 * 1024 * 4);
    short* wqkv  = (short*)nalloc((size_t)4 * 3072 * 1024 * 2);
    short* wo    = (short*)nalloc((size_t)4 * 1024 * 1024 * 2);
    short* w1    = (short*)nalloc((size_t)4 * 4096 * 1024 * 2);
    short* w2    = (short*)nalloc((size_t)4 * 1024 * 4096 * 2);
    short* wh    = (short*)nalloc((size_t)32000 * 1024 * 2);
    float* bqkv  = (float*)nalloc((size_t)4 * 3072 * 4);

    // ---- weight prep (single dispatch incl. bias concat) ----
    k_tconv_all<<<20336, 256, 0, stream>>>(Wq, Wk, Wv, Wo, W1, W2, headw,
                                           bq, bk, bv,
                                           wqkv, wo, w1, w2, wh, bqkv);

    // ---- forward ----
    k_embedln<<<2048, 256, 0, stream>>>(idx, tok, pos, ln1w, ln1b, x, h);
    for (int lyr = 0; lyr < 4; lyr++) {
        k_gemm<2, 4><<<768, 256, 0, stream>>>(h, wqkv + (size_t)lyr * 3072 * 1024, bqkv + lyr * 3072,
                                              nullptr, qkv, vtb, 2048, 3072, 1024, 1024, 32, 1);
        k_attn<<<dim3(32, 32), 256, 0, stream>>>(qkv, vtb, y);
        k_gemm<2, 1><<<256, 256, 0, stream>>>(y, wo + (size_t)lyr * 1024 * 1024, bo + lyr * 1024,
                                              x, x, nullptr, 2048, 1024, 1024, 1024, 32, 1);
        k_ln<<<2048, 256, 0, stream>>>(x, ln2w + lyr * 1024, ln2b + lyr * 1024, h);
        k_gemm<4, 2><<<512, 256, 0, stream>>>(h, w1 + (size_t)lyr * 4194304, b1 + lyr * 4096,
                                              nullptr, u, nullptr, 2048, 4096, 1024, 1024, 16, 1);
        k_gemm<4, 3><<<512, 256, 0, stream>>>(u, w2 + (size_t)lyr * 4194304, nullptr,
                                              nullptr, mpart, nullptr, 2048, 1024, 4096, 1024, 16, 4);
        const float* nw = (lyr < 3) ? (ln1w + (lyr + 1) * 1024) : lnfw;
        const float* nb = (lyr < 3) ? (ln1b + (lyr + 1) * 1024) : lnfb;
        k_redln<<<2048, 256, 0, stream>>>(mpart, b2 + lyr * 1024, x, nw, nb, h);
    }
    k_gemm8<<<1000, 512, 0, stream>>>(h, wh, (float*)d_out, 2048, 32000, 1024, 8);
    (void)in_sizes; (void)n_in; (void)out_size; (void)ws_size;
}

// Round 12
// 915.450 us; speedup vs baseline: 1.0638x; 1.0638x over previous
//
#include <hip/hip_runtime.h>
#include <hip/hip_bf16.h>

// GPT forward: B=2, T=1024, D=1024, H=16, HD=64, L=4, V=32000
// R12: attn reverted to R10 version (kv-split regressed: 4x per-block fixed
//      costs > occupancy gain). O-proj now split-K x2 (512 blocks = 2/CU) with
//      fused k_redln2 (partials+bias+residual+LN2). k_ln deleted.

typedef __attribute__((ext_vector_type(8))) short s16x8;
typedef __attribute__((ext_vector_type(4))) float fx4;

__device__ __forceinline__ unsigned short f2bf(float f) {
    union { float f; unsigned int u; } v; v.f = f;
    unsigned int r = v.u + 0x7FFFu + ((v.u >> 16) & 1u);
    return (unsigned short)(r >> 16);
}

__device__ __forceinline__ void gload16(const short* g, short* l) {
    __builtin_amdgcn_global_load_lds((const __attribute__((address_space(1))) void*)g,
                                     (__attribute__((address_space(3))) void*)l, 16, 0, 0);
}

__device__ __forceinline__ unsigned cvtpk(float a, float b) {
    unsigned r;
    asm("v_cvt_pk_bf16_f32 %0, %1, %2" : "=v"(r) : "v"(a), "v"(b));
    return r;
}

// ---------------- embed + LN fused (row-local) ----------------
__global__ __launch_bounds__(256) void k_embedln(const int* __restrict__ idx,
                                                 const float* __restrict__ tok,
                                                 const float* __restrict__ pos,
                                                 const float* __restrict__ lw,
                                                 const float* __restrict__ lb,
                                                 float* __restrict__ x,
                                                 short* __restrict__ out) {
    int r = blockIdx.x;
    int t = r & 1023;
    int tokid = idx[r];
    int tid = threadIdx.x;
    float4 v = ((const float4*)(tok + (size_t)tokid * 1024))[tid];
    float4 vp = ((const float4*)(pos + (size_t)t * 1024))[tid];
    v.x += vp.x; v.y += vp.y; v.z += vp.z; v.w += vp.w;
    ((float4*)(x + (size_t)r * 1024))[tid] = v;
    float s = v.x + v.y + v.z + v.w;
    float ss = v.x*v.x + v.y*v.y + v.z*v.z + v.w*v.w;
    __shared__ float red[8];
    #pragma unroll
    for (int off = 32; off; off >>= 1) { s += __shfl_down(s, off); ss += __shfl_down(ss, off); }
    int wid = tid >> 6;
    if ((tid & 63) == 0) { red[wid] = s; red[4 + wid] = ss; }
    __syncthreads();
    s = red[0] + red[1] + red[2] + red[3];
    ss = red[4] + red[5] + red[6] + red[7];
    float mean = s * (1.0f / 1024.0f);
    float var = ss * (1.0f / 1024.0f) - mean * mean;
    float rstd = rsqrtf(var + 1e-5f);
    float4 wv = ((const float4*)lw)[tid];
    float4 bv = ((const float4*)lb)[tid];
    union { unsigned short us[4]; unsigned long long ll; } pk;
    pk.us[0] = f2bf((v.x - mean) * rstd * wv.x + bv.x);
    pk.us[1] = f2bf((v.y - mean) * rstd * wv.y + bv.y);
    pk.us[2] = f2bf((v.z - mean) * rstd * wv.z + bv.z);
    pk.us[3] = f2bf((v.w - mean) * rstd * wv.w + bv.w);
    ((unsigned long long*)(out + (size_t)r * 1024))[tid] = pk.ll;
}

// ---------------- splitK(2) reduce + bias + residual + LN fused ----------------
__global__ __launch_bounds__(256) void k_redln2(const float* __restrict__ part,
                                                const float* __restrict__ bias,
                                                float* __restrict__ x,
                                                const float* __restrict__ lw,
                                                const float* __restrict__ lb,
                                                short* __restrict__ out) {
    const size_t PS = (size_t)2048 * 1024;
    const int r = blockIdx.x;
    const int tid = threadIdx.x;
    const size_t base = (size_t)r * 1024 + tid * 4;
    float4 a = *(const float4*)(part + base);
    float4 b = *(const float4*)(part + PS + base);
    float4 v = *(const float4*)(x + base);
    float4 bb = *(const float4*)(bias + tid * 4);
    v.x += a.x + b.x + bb.x;
    v.y += a.y + b.y + bb.y;
    v.z += a.z + b.z + bb.z;
    v.w += a.w + b.w + bb.w;
    *(float4*)(x + base) = v;
    float s = v.x + v.y + v.z + v.w;
    float ss = v.x*v.x + v.y*v.y + v.z*v.z + v.w*v.w;
    __shared__ float red[8];
    #pragma unroll
    for (int off = 32; off; off >>= 1) { s += __shfl_down(s, off); ss += __shfl_down(ss, off); }
    int wid = tid >> 6;
    if ((tid & 63) == 0) { red[wid] = s; red[4 + wid] = ss; }
    __syncthreads();
    s = red[0] + red[1] + red[2] + red[3];
    ss = red[4] + red[5] + red[6] + red[7];
    float mean = s * (1.0f / 1024.0f);
    float var = ss * (1.0f / 1024.0f) - mean * mean;
    float rstd = rsqrtf(var + 1e-5f);
    float4 wv = ((const float4*)lw)[tid];
    float4 bv = ((const float4*)lb)[tid];
    union { unsigned short us[4]; unsigned long long ll; } pk;
    pk.us[0] = f2bf((v.x - mean) * rstd * wv.x + bv.x);
    pk.us[1] = f2bf((v.y - mean) * rstd * wv.y + bv.y);
    pk.us[2] = f2bf((v.z - mean) * rstd * wv.z + bv.z);
    pk.us[3] = f2bf((v.w - mean) * rstd * wv.w + bv.w);
    ((unsigned long long*)(out + (size_t)r * 1024))[tid] = pk.ll;
}

// ---------------- splitK(4) reduce + bias + residual + LN fused ----------------
__global__ __launch_bounds__(256) void k_redln(const float* __restrict__ part,
                                               const float* __restrict__ bias,
                                               float* __restrict__ x,
                                               const float* __restrict__ lw,
                                               const float* __restrict__ lb,
                                               short* __restrict__ out) {
    const size_t PS = (size_t)2048 * 1024;
    const int r = blockIdx.x;
    const int tid = threadIdx.x;
    const size_t base = (size_t)r * 1024 + tid * 4;
    float4 a = *(const float4*)(part + base);
    float4 b = *(const float4*)(part + PS + base);
    float4 c = *(const float4*)(part + 2 * PS + base);
    float4 d = *(const float4*)(part + 3 * PS + base);
    float4 v = *(const float4*)(x + base);
    float4 bb = *(const float4*)(bias + tid * 4);
    v.x += a.x + b.x + c.x + d.x + bb.x;
    v.y += a.y + b.y + c.y + d.y + bb.y;
    v.z += a.z + b.z + c.z + d.z + bb.z;
    v.w += a.w + b.w + c.w + d.w + bb.w;
    *(float4*)(x + base) = v;
    float s = v.x + v.y + v.z + v.w;
    float ss = v.x*v.x + v.y*v.y + v.z*v.z + v.w*v.w;
    __shared__ float red[8];
    #pragma unroll
    for (int off = 32; off; off >>= 1) { s += __shfl_down(s, off); ss += __shfl_down(ss, off); }
    int wid = tid >> 6;
    if ((tid & 63) == 0) { red[wid] = s; red[4 + wid] = ss; }
    __syncthreads();
    s = red[0] + red[1] + red[2] + red[3];
    ss = red[4] + red[5] + red[6] + red[7];
    float mean = s * (1.0f / 1024.0f);
    float var = ss * (1.0f / 1024.0f) - mean * mean;
    float rstd = rsqrtf(var + 1e-5f);
    float4 wv = ((const float4*)lw)[tid];
    float4 bv = ((const float4*)lb)[tid];
    union { unsigned short us[4]; unsigned long long ll; } pk;
    pk.us[0] = f2bf((v.x - mean) * rstd * wv.x + bv.x);
    pk.us[1] = f2bf((v.y - mean) * rstd * wv.y + bv.y);
    pk.us[2] = f2bf((v.z - mean) * rstd * wv.z + bv.z);
    pk.us[3] = f2bf((v.w - mean) * rstd * wv.w + bv.w);
    ((unsigned long long*)(out + (size_t)r * 1024))[tid] = pk.ll;
}

// ---------------- batched transpose+convert (+ qkv-bias concat), one dispatch ----------------
__global__ __launch_bounds__(256) void k_tconv_all(
        const float* __restrict__ Wq, const float* __restrict__ Wk,
        const float* __restrict__ Wv, const float* __restrict__ Wo,
        const float* __restrict__ W1, const float* __restrict__ W2,
        const float* __restrict__ Wh,
        const float* __restrict__ bq, const float* __restrict__ bk,
        const float* __restrict__ bv,
        short* __restrict__ wqkv, short* __restrict__ wo,
        short* __restrict__ w1, short* __restrict__ w2, short* __restrict__ wh,
        float* __restrict__ bqkv) {
    const int bid = blockIdx.x;
    if (bid >= 20288) {
        int i = (bid - 20288) * 256 + threadIdx.x;
        int lq = i / 3072, c = i % 3072;
        float v = (c < 1024) ? bq[lq*1024 + c] : ((c < 2048) ? bk[lq*1024 + c - 1024] : bv[lq*1024 + c - 2048]);
        bqkv[i] = v;
        return;
    }
    const float* src; short* dst; int K, N, tile;
    if (bid < 4096) {
        int seg = bid >> 10;
        int r = bid & 1023;
        int l = r >> 8; tile = r & 255;
        K = 1024; N = 1024;
        if (seg == 0)      { src = Wq + (size_t)l * 1048576; dst = wqkv + (size_t)l * 3145728; }
        else if (seg == 1) { src = Wk + (size_t)l * 1048576; dst = wqkv + (size_t)l * 3145728 + 1048576; }
        else if (seg == 2) { src = Wv + (size_t)l * 1048576; dst = wqkv + (size_t)l * 3145728 + 2097152; }
        else               { src = Wo + (size_t)l * 1048576; dst = wo + (size_t)l * 1048576; }
    } else if (bid < 8192) {
        int r = bid - 4096; int l = r >> 10; tile = r & 1023;
        K = 1024; N = 4096; src = W1 + (size_t)l * 4194304; dst = w1 + (size_t)l * 4194304;
    } else if (bid < 12288) {
        int r = bid - 8192; int l = r >> 10; tile = r & 1023;
        K = 4096; N = 1024; src = W2 + (size_t)l * 4194304; dst = w2 + (size_t)l * 4194304;
    } else {
        tile = bid - 12288; K = 1024; N = 32000; src = Wh; dst = wh;
    }
    const int nTiles = N >> 6;
    const int kt = tile / nTiles, ntl = tile - kt * nTiles;
    const int n0 = ntl * 64, k0 = kt * 64;

    __shared__ float tl[64][65];
    const int tid = threadIdx.x;
    const int c4 = tid & 15, rr = tid >> 4;
    #pragma unroll
    for (int j = 0; j < 4; j++) {
        int row = rr + j * 16;
        float4 vv = *(const float4*)(src + (size_t)(k0 + row) * N + n0 + c4 * 4);
        tl[row][c4*4+0] = vv.x; tl[row][c4*4+1] = vv.y;
        tl[row][c4*4+2] = vv.z; tl[row][c4*4+3] = vv.w;
    }
    __syncthreads();
    const int c8 = tid & 7, r2 = tid >> 3;
    #pragma unroll
    for (int j = 0; j < 2; j++) {
        int nrow = r2 + j * 32;
        union { unsigned short us[8]; s16x8 v; } pk;
        #pragma unroll
        for (int e = 0; e < 8; e++) pk.us[e] = f2bf(tl[c8*8+e][nrow]);
        *(s16x8*)&dst[(size_t)(n0 + nrow) * K + k0 + c8 * 8] = pk.v;
    }
}

// ---------------- 128-class GEMM (m97 structure), EPI + split-K support ----------------
// EPI: 0 = bias->bf16; 1 = f32 + residual; 2 = bias+GELU->bf16; 3 = f32 partial
// (no bias); 4 = QKV: bias->bf16 for Q/K cols, V cols transposed bf16 -> vtout
template<int MF, int EPI>
__global__ __launch_bounds__(256) void k_gemm(const short* __restrict__ A, const short* __restrict__ Bt,
                                              const float* bias, const float* res, void* Cout,
                                              short* vtout,
                                              int M, int N, int Kstride, int kLen,
                                              int mTiles, int nParts) {
    constexpr int BM = MF * 32;
    constexpr int IA = BM / 32;
    __shared__ __align__(16) short lA[BM * 64];
    __shared__ __align__(16) short lB[128 * 64];
    const int tid = threadIdx.x;
    const int l = tid & 63, w = tid >> 6;
    const int wr = w >> 1, wc = w & 1;
    const int per = gridDim.x >> 3;
    const int s2 = (blockIdx.x & 7) * per + (blockIdx.x >> 3);
    const int totPerN = mTiles * nParts;
    const int nt = s2 / totPerN;
    const int rem = s2 - nt * totPerN;
    const int part = rem / mTiles, mt = rem - part * mTiles;
    const int k0 = part * kLen;
    const int m0 = mt * BM, n0 = nt * 128;
    const int cl = l & 15, rh = l >> 4;
    fx4 acc[MF][4] = {};

    const int lr = l >> 3, c8 = l & 7;
    const short* pa[IA];
    const short* pb[4];
    #pragma unroll
    for (int j = 0; j < IA; j++) {
        const int row = w * (BM / 4) + j * 8 + lr;
        pa[j] = A + (size_t)(m0 + row) * Kstride + k0 + ((c8 ^ (row & 7)) << 3);
    }
    #pragma unroll
    for (int j = 0; j < 4; j++) {
        const int row = w * 32 + j * 8 + lr;
        pb[j] = Bt + (size_t)(n0 + row) * Kstride + k0 + ((c8 ^ (row & 7)) << 3);
    }

    for (int kt = 0; kt < kLen; kt += 64) {
        #pragma unroll
        for (int j = 0; j < IA; j++)
            gload16(pa[j] + kt, &lA[(w * (BM / 4) + j * 8) * 64]);
        #pragma unroll
        for (int j = 0; j < 4; j++)
            gload16(pb[j] + kt, &lB[(w * 32 + j * 8) * 64]);
        __syncthreads();
        #pragma unroll
        for (int kk = 0; kk < 2; kk++) {
            s16x8 af[MF], bfr[4];
            const int kc = kk * 4 + rh;
            const int ko = (kc ^ (cl & 7)) * 8;
            #pragma unroll
            for (int mf = 0; mf < MF; mf++)
                af[mf] = *(const s16x8*)&lA[(wr * (MF * 16) + mf * 16 + cl) * 64 + ko];
            #pragma unroll
            for (int nf = 0; nf < 4; nf++)
                bfr[nf] = *(const s16x8*)&lB[(wc * 64 + nf * 16 + cl) * 64 + ko];
            #pragma unroll
            for (int mf = 0; mf < MF; mf++)
                #pragma unroll
                for (int nf = 0; nf < 4; nf++)
                    acc[mf][nf] = __builtin_amdgcn_mfma_f32_16x16x32_bf16(af[mf], bfr[nf], acc[mf][nf], 0, 0, 0);
        }
        __syncthreads();
    }
    float* Cp = (float*)Cout + (size_t)part * M * N;
    #pragma unroll
    for (int nf = 0; nf < 4; nf++) {
        const int col = n0 + wc * 64 + nf * 16 + cl;
        const float bv = (EPI == 3) ? 0.0f : bias[col];
        #pragma unroll
        for (int mf = 0; mf < MF; mf++) {
            const int rbase = m0 + wr * (MF * 16) + mf * 16 + rh * 4;
            if constexpr (EPI == 4) {
                float vv[4];
                #pragma unroll
                for (int r = 0; r < 4; r++) vv[r] = acc[mf][nf][r] + bv;
                if (n0 >= 2048) {
                    const int cc = col - 2048;
                    const int bidx = rbase >> 10, t0v = rbase & 1023;
                    uint2 pk2;
                    pk2.x = cvtpk(vv[0], vv[1]);
                    pk2.y = cvtpk(vv[2], vv[3]);
                    *(uint2*)&vtout[(size_t)((bidx * 16 + (cc >> 6)) * 64 + (cc & 63)) * 1024 + t0v] = pk2;
                } else {
                    #pragma unroll
                    for (int r = 0; r < 4; r++)
                        ((unsigned short*)Cout)[(size_t)(rbase + r) * N + col] = f2bf(vv[r]);
                }
            } else {
                #pragma unroll
                for (int r = 0; r < 4; r++) {
                    float v = acc[mf][nf][r] + bv;
                    const size_t off = (size_t)(rbase + r) * N + col;
                    if constexpr (EPI == 0) {
                        ((unsigned short*)Cout)[off] = f2bf(v);
                    } else if constexpr (EPI == 1) {
                        ((float*)Cout)[off] = v + res[off];
                    } else if constexpr (EPI == 2) {
                        v = 0.5f * v * (1.0f + erff(v * 0.70710678118654752f));
                        ((unsigned short*)Cout)[off] = f2bf(v);
                    } else {
                        Cp[off] = v;
                    }
                }
            }
        }
    }
}

// ---------------- 8-phase 256x256 GEMM (head), f32 out, no bias ----------------
#define PH_CORE(MB) \
    __builtin_amdgcn_s_barrier(); \
    __builtin_amdgcn_s_setprio(1); \
    _Pragma("unroll") \
    for (int nf_ = 0; nf_ < 4; ++nf_) { \
        acc[MB][nf_]   = __builtin_amdgcn_mfma_f32_16x16x32_bf16(af[0][0], bf[nf_][0], acc[MB][nf_], 0, 0, 0); \
        acc[MB][nf_]   = __builtin_amdgcn_mfma_f32_16x16x32_bf16(af[0][1], bf[nf_][1], acc[MB][nf_], 0, 0, 0); \
        acc[MB+1][nf_] = __builtin_amdgcn_mfma_f32_16x16x32_bf16(af[1][0], bf[nf_][0], acc[MB+1][nf_], 0, 0, 0); \
        acc[MB+1][nf_] = __builtin_amdgcn_mfma_f32_16x16x32_bf16(af[1][1], bf[nf_][1], acc[MB+1][nf_], 0, 0, 0); \
    } \
    __builtin_amdgcn_s_setprio(0);

#define PHN(MB) \
    PH_CORE(MB) \
    asm volatile("" ::: "memory"); \
    __builtin_amdgcn_s_barrier(); \
    asm volatile("" ::: "memory");

#define PHW(MB) \
    PH_CORE(MB) \
    asm volatile("s_waitcnt vmcnt(4)" ::: "memory"); \
    __builtin_amdgcn_s_barrier(); \
    asm volatile("" ::: "memory");

__global__ __launch_bounds__(512, 1)
void k_gemm8(const short* __restrict__ A, const short* __restrict__ Bt,
             float* __restrict__ C, int M, int N, int K, int mTiles) {
    __shared__ __align__(16) short lA[2][256 * 64];
    __shared__ __align__(16) short lB[2][256 * 64];
    const int tid = threadIdx.x;
    const int l = tid & 63, w = tid >> 6;
    const int wr = w >> 2, wc = w & 3;
    const int per = gridDim.x >> 3;
    const int s2 = (blockIdx.x & 7) * per + (blockIdx.x >> 3);
    const int nt0 = s2 / mTiles, mt = s2 - nt0 * mTiles;
    const int m0 = mt * 256, n0 = nt0 * 256;
    const int cl = l & 15, rh = l >> 4;

    fx4 acc[8][4] = {};

    const int srow = tid >> 3, sc8 = tid & 7;
    const short* pA[2][2]; const short* pB[2][2];
    #pragma unroll
    for (int hh = 0; hh < 2; ++hh)
        #pragma unroll
        for (int j = 0; j < 2; ++j) {
            const int row = hh * 128 + j * 64 + srow;
            const int cg = (sc8 ^ (row & 7)) << 3;
            pA[hh][j] = A + (size_t)(m0 + row) * K + cg;
            pB[hh][j] = Bt + (size_t)(n0 + row) * K + cg;
        }

    auto stageA = [&](int b, int hh, int kt) {
        #pragma unroll
        for (int j = 0; j < 2; ++j)
            gload16(pA[hh][j] + (kt << 6), &lA[b][(hh * 128 + j * 64 + w * 8) * 64]);
    };
    auto stageB = [&](int b, int hh, int kt) {
        #pragma unroll
        for (int j = 0; j < 2; ++j)
            gload16(pB[hh][j] + (kt << 6), &lB[b][(hh * 128 + j * 64 + w * 8) * 64]);
    };
    auto readA = [&](int b, int mf, int kk) -> s16x8 {
        const int row = wr * 128 + mf * 16 + cl;
        return *(const s16x8*)&lA[b][(row << 6) + (((kk * 4 + rh) ^ (row & 7)) << 3)];
    };
    auto readB = [&](int b, int nf, int kk) -> s16x8 {
        const int row = wc * 64 + nf * 16 + cl;
        return *(const s16x8*)&lB[b][(row << 6) + (((kk * 4 + rh) ^ (row & 7)) << 3)];
    };

    const int NT = K >> 6;
    stageA(0, 0, 0); stageA(0, 1, 0);
    stageB(0, 0, 0); stageB(0, 1, 0);
    stageB(1, 0, 1); stageB(1, 1, 1);
    asm volatile("s_waitcnt vmcnt(4)" ::: "memory");
    __builtin_amdgcn_s_barrier();
    asm volatile("" ::: "memory");

    s16x8 bf[4][2], af[2][2];
    for (int c = 0; c < (NT >> 1); ++c) {
        const int kt = c << 1;
        const int k1 = kt + 1;
        const int k2 = (kt + 2 < NT) ? kt + 2 : NT - 1;
        const int k3 = (kt + 3 < NT) ? kt + 3 : NT - 1;

        #pragma unroll
        for (int nf = 0; nf < 4; ++nf) { bf[nf][0] = readB(0, nf, 0); bf[nf][1] = readB(0, nf, 1); }
        af[0][0] = readA(0, 0, 0); af[0][1] = readA(0, 0, 1);
        af[1][0] = readA(0, 1, 0); af[1][1] = readA(0, 1, 1);
        stageA(1, 0, k1); stageA(1, 1, k1);
        PHN(0)
        af[0][0] = readA(0, 2, 0); af[0][1] = readA(0, 2, 1);
        af[1][0] = readA(0, 3, 0); af[1][1] = readA(0, 3, 1);
        stageB(0, 0, k2);
        PHN(2)
        af[0][0] = readA(0, 4, 0); af[0][1] = readA(0, 4, 1);
        af[1][0] = readA(0, 5, 0); af[1][1] = readA(0, 5, 1);
        stageB(0, 1, k2);
        PHN(4)
        af[0][0] = readA(0, 6, 0); af[0][1] = readA(0, 6, 1);
        af[1][0] = readA(0, 7, 0); af[1][1] = readA(0, 7, 1);
        PHW(6)
        #pragma unroll
        for (int nf = 0; nf < 4; ++nf) { bf[nf][0] = readB(1, nf, 0); bf[nf][1] = readB(1, nf, 1); }
        af[0][0] = readA(1, 0, 0); af[0][1] = readA(1, 0, 1);
        af[1][0] = readA(1, 1, 0); af[1][1] = readA(1, 1, 1);
        stageA(0, 0, k2);
        PHN(0)
        af[0][0] = readA(1, 2, 0); af[0][1] = readA(1, 2, 1);
        af[1][0] = readA(1, 3, 0); af[1][1] = readA(1, 3, 1);
        stageA(0, 1, k2);
        PHN(2)
        af[0][0] = readA(1, 4, 0); af[0][1] = readA(1, 4, 1);
        af[1][0] = readA(1, 5, 0); af[1][1] = readA(1, 5, 1);
        stageB(1, 0, k3);
        PHN(4)
        af[0][0] = readA(1, 6, 0); af[0][1] = readA(1, 6, 1);
        af[1][0] = readA(1, 7, 0); af[1][1] = readA(1, 7, 1);
        stageB(1, 1, k3);
        PHW(6)
    }

    float* eld = (float*)((char*)&lA[0][0] + w * 4352);
    const int erow = l >> 4, ec4 = (l & 15) * 4;
    #pragma unroll
    for (int mf = 0; mf < 8; ++mf) {
        #pragma unroll
        for (int nf = 0; nf < 4; ++nf)
            #pragma unroll
            for (int r = 0; r < 4; ++r)
                eld[(rh * 4 + r) * 68 + nf * 16 + cl] = acc[mf][nf][r];
        asm volatile("s_waitcnt lgkmcnt(0)" ::: "memory");
        #pragma unroll
        for (int s = 0; s < 4; ++s) {
            const int rr2 = s * 4 + erow;
            float4 vv = *(const float4*)&eld[rr2 * 68 + ec4];
            *(float4*)&C[(size_t)(m0 + wr * 128 + mf * 16 + rr2) * N + n0 + wc * 64 + ec4] = vv;
        }
        asm volatile("s_waitcnt lgkmcnt(0)" ::: "memory");
    }
}

// ---------------- fused causal attention (R10 version): swapped QK^T, global K/V ----------------
__global__ __launch_bounds__(256) void k_attn(const short* __restrict__ qkv,
                                              const short* __restrict__ vt,
                                              short* __restrict__ y) {
    const int bh = blockIdx.y, qt = blockIdx.x;
    const int b = bh >> 4, h = bh & 15;
    const int w = threadIdx.x >> 6, l = threadIdx.x & 63;
    const int cl = l & 15, rh = l >> 4;
    const int q0 = qt * 128 + w * 32;
    const short* qbase = qkv + (size_t)b * 1024 * 3072 + h * 64;
    const short* kbase = qbase + 1024;
    const short* vbase = vt + (size_t)bh * 64 * 1024;
    __shared__ __align__(16) short plds[4][32][64];
    char* pbase = (char*)&plds[w][0][0];

    s16x8 qf[2][2];
    #pragma unroll
    for (int n = 0; n < 2; n++)
        #pragma unroll
        for (int kf = 0; kf < 2; kf++)
            qf[n][kf] = *(const s16x8*)&qbase[(size_t)(q0 + n * 16 + cl) * 3072 + kf * 32 + rh * 8];

    fx4 oacc[4][2] = {};
    float mrow[2] = {-3e38f, -3e38f}, lrow[2] = {0.0f, 0.0f};
    const float SC = 0.125f * 1.44269504088896f;

    const int ntile = (q0 + 95) >> 6;
    for (int it = 0; it < ntile; it++) {
        const int t0 = it * 64;
        fx4 s[4][2] = {};
        #pragma unroll
        for (int kf = 0; kf < 2; kf++) {
            s16x8 kfr[4];
            #pragma unroll
            for (int m = 0; m < 4; m++)
                kfr[m] = *(const s16x8*)&kbase[(size_t)(t0 + m * 16 + cl) * 3072 + kf * 32 + rh * 8];
            #pragma unroll
            for (int m = 0; m < 4; m++)
                #pragma unroll
                for (int n = 0; n < 2; n++)
                    s[m][n] = __builtin_amdgcn_mfma_f32_16x16x32_bf16(kfr[m], qf[n][kf], s[m][n], 0, 0, 0);
        }
        const bool domask = (t0 + 63) > q0;
        #pragma unroll
        for (int n = 0; n < 2; n++) {
            const int q = q0 + n * 16 + cl;
            float tmax = -3e38f;
            #pragma unroll
            for (int m = 0; m < 4; m++)
                #pragma unroll
                for (int r = 0; r < 4; r++) {
                    float v = s[m][n][r] * SC;
                    if (domask && (t0 + m * 16 + rh * 4 + r) > q) v = -3e38f;
                    s[m][n][r] = v;
                    tmax = fmaxf(tmax, v);
                }
            tmax = fmaxf(tmax, __shfl_xor(tmax, 16));
            tmax = fmaxf(tmax, __shfl_xor(tmax, 32));
            const float mnew = fmaxf(mrow[n], tmax);
            const float alpha = exp2f(mrow[n] - mnew);
            mrow[n] = mnew;
            float rsum = 0.0f;
            #pragma unroll
            for (int m = 0; m < 4; m++)
                #pragma unroll
                for (int r = 0; r < 4; r++) {
                    float p = exp2f(s[m][n][r] - mnew);
                    s[m][n][r] = p;
                    rsum += p;
                }
            rsum += __shfl_xor(rsum, 16);
            rsum += __shfl_xor(rsum, 32);
            lrow[n] = lrow[n] * alpha + rsum;
            #pragma unroll
            for (int mp = 0; mp < 4; mp++)
                #pragma unroll
                for (int r = 0; r < 4; r++)
                    oacc[mp][n][r] *= alpha;
        }
        #pragma unroll
        for (int n = 0; n < 2; n++) {
            const int qr = n * 16 + cl;
            const int sw = (qr & 7) << 4;
            #pragma unroll
            for (int m = 0; m < 4; m++) {
                uint2 pk2;
                pk2.x = cvtpk(s[m][n][0], s[m][n][1]);
                pk2.y = cvtpk(s[m][n][2], s[m][n][3]);
                const int off = qr * 128 + ((m * 32 + rh * 8) ^ sw);
                *(uint2*)(pbase + off) = pk2;
            }
        }
        s16x8 pb2[2][2];
        #pragma unroll
        for (int n = 0; n < 2; n++) {
            const int qr = n * 16 + cl;
            const int sw = (qr & 7) << 4;
            #pragma unroll
            for (int kf = 0; kf < 2; kf++)
                pb2[n][kf] = *(const s16x8*)(pbase + qr * 128 + ((kf * 64 + rh * 16) ^ sw));
        }
        s16x8 vf[4][2];
        #pragma unroll
        for (int mp = 0; mp < 4; mp++)
            #pragma unroll
            for (int kf = 0; kf < 2; kf++)
                vf[mp][kf] = *(const s16x8*)&vbase[(size_t)(mp * 16 + cl) * 1024 + t0 + kf * 32 + rh * 8];
        #pragma unroll
        for (int mp = 0; mp < 4; mp++)
            #pragma unroll
            for (int n = 0; n < 2; n++)
                #pragma unroll
                for (int kf = 0; kf < 2; kf++)
                    oacc[mp][n] = __builtin_amdgcn_mfma_f32_16x16x32_bf16(vf[mp][kf], pb2[n][kf], oacc[mp][n], 0, 0, 0);
    }
    #pragma unroll
    for (int n = 0; n < 2; n++) {
        const float inv = 1.0f / lrow[n];
        const int q = q0 + n * 16 + cl;
        #pragma unroll
        for (int mp = 0; mp < 4; mp++) {
            uint2 pk2;
            pk2.x = cvtpk(oacc[mp][n][0] * inv, oacc[mp][n][1] * inv);
            pk2.y = cvtpk(oacc[mp][n][2] * inv, oacc[mp][n][3] * inv);
            *(uint2*)&y[(size_t)(b * 1024 + q) * 1024 + h * 64 + mp * 16 + rh * 4] = pk2;
        }
    }
}

// ---------------- host launcher ----------------
extern "C" void kernel_launch(void* const* d_in, const int* in_sizes, int n_in,
                              void* d_out, int out_size, void* d_ws, size_t ws_size,
                              hipStream_t stream) {
    const int*   idx   = (const int*)d_in[0];
    const float* tok   = (const float*)d_in[1];
    const float* pos   = (const float*)d_in[2];
    const float* ln1w  = (const float*)d_in[3];
    const float* ln1b  = (const float*)d_in[4];
    const float* Wq    = (const float*)d_in[5];
    const float* bq    = (const float*)d_in[6];
    const float* Wk    = (const float*)d_in[7];
    const float* bk    = (const float*)d_in[8];
    const float* Wv    = (const float*)d_in[9];
    const float* bv    = (const float*)d_in[10];
    const float* Wo    = (const float*)d_in[11];
    const float* bo    = (const float*)d_in[12];
    const float* ln2w  = (const float*)d_in[13];
    const float* ln2b  = (const float*)d_in[14];
    const float* W1    = (const float*)d_in[15];
    const float* b1    = (const float*)d_in[16];
    const float* W2    = (const float*)d_in[17];
    const float* b2    = (const float*)d_in[18];
    const float* lnfw  = (const float*)d_in[19];
    const float* lnfb  = (const float*)d_in[20];
    const float* headw = (const float*)d_in[21];

    char* ws = (char*)d_ws;
    size_t off = 0;
    auto nalloc = [&](size_t bytes) -> char* {
        char* p = ws + off;
        off = (off + bytes + 255) & ~(size_t)255;
        return p;
    };
    float* x     = (float*)nalloc((size_t)2048 * 1024 * 4);
    short* h     = (short*)nalloc((size_t)2048 * 1024 * 2);
    short* qkv   = (short*)nalloc((size_t)2048 * 3072 * 2);
    short* vtb   = (short*)nalloc((size_t)32 * 64 * 1024 * 2);
    short* y     = (short*)nalloc((size_t)2048 * 1024 * 2);
    short* u     = (short*)nalloc((size_t)2048 * 4096 * 2);
    float* mpart = (float*)nalloc((size_t)4 * 2048 * 1024 * 4);
    short* wqkv  = (short*)nalloc((size_t)4 * 3072 * 1024 * 2);
    short* wo    = (short*)nalloc((size_t)4 * 1024 * 1024 * 2);
    short* w1    = (short*)nalloc((size_t)4 * 4096 * 1024 * 2);
    short* w2    = (short*)nalloc((size_t)4 * 1024 * 4096 * 2);
    short* wh    = (short*)nalloc((size_t)32000 * 1024 * 2);
    float* bqkv  = (float*)nalloc((size_t)4 * 3072 * 4);

    // ---- weight prep (single dispatch incl. bias concat) ----
    k_tconv_all<<<20336, 256, 0, stream>>>(Wq, Wk, Wv, Wo, W1, W2, headw,
                                           bq, bk, bv,
                                           wqkv, wo, w1, w2, wh, bqkv);

    // ---- forward ----
    k_embedln<<<2048, 256, 0, stream>>>(idx, tok, pos, ln1w, ln1b, x, h);
    for (int lyr = 0; lyr < 4; lyr++) {
        k_gemm<2, 4><<<768, 256, 0, stream>>>(h, wqkv + (size_t)lyr * 3072 * 1024, bqkv + lyr * 3072,
                                              nullptr, qkv, vtb, 2048, 3072, 1024, 1024, 32, 1);
        k_attn<<<dim3(8, 32), 256, 0, stream>>>(qkv, vtb, y);
        k_gemm<2, 3><<<512, 256, 0, stream>>>(y, wo + (size_t)lyr * 1024 * 1024, nullptr,
                                              nullptr, mpart, nullptr, 2048, 1024, 1024, 512, 32, 2);
        k_redln2<<<2048, 256, 0, stream>>>(mpart, bo + lyr * 1024, x,
                                           ln2w + lyr * 1024, ln2b + lyr * 1024, h);
        k_gemm<4, 2><<<512, 256, 0, stream>>>(h, w1 + (size_t)lyr * 4194304, b1 + lyr * 4096,
                                              nullptr, u, nullptr, 2048, 4096, 1024, 1024, 16, 1);
        k_gemm<4, 3><<<512, 256, 0, stream>>>(u, w2 + (size_t)lyr * 4194304, nullptr,
                                              nullptr, mpart, nullptr, 2048, 1024, 4096, 1024, 16, 4);
        const float* nw = (lyr < 3) ? (ln1w + (lyr + 1) * 1024) : lnfw;
        const float* nb = (lyr < 3) ? (ln1b + (lyr + 1) * 1024) : lnfb;
        k_redln<<<2048, 256, 0, stream>>>(mpart, b2 + lyr * 1024, x, nw, nb, h);
    }
    k_gemm8<<<1000, 512, 0, stream>>>(h, wh, (float*)d_out, 2048, 32000, 1024, 8);
    (void)in_sizes; (void)n_in; (void)out_size; (void)ws_size;
}